// Round 1
// baseline (11329.440 us; speedup 1.0000x reference)
//
#include <hip/hip_runtime.h>
#include <hip/hip_bf16.h>

// PPOActorRNN: T=256, B=256, D=512, A=32, L=3
// Phases:
//  1) MLP encoder: 3x (GEMM 512x512 + bias + LN + ReLU), in-place on obs buffer
//  2) Xi = E @ Wi[g] + bi[g] for g=0..2  (one GEMM, grid.y = gate) -> workspace
//  3) sequential GRU, 256 steps; per step only h@Wh[g] + gates; y -> obs buffer
//  4) head: GEMM + bias + LN + ReLU in-place on obs buffer (reuses kernel 1)
//  5) logits = AM @ Wa + ba, avail masking -> d_out
// Recurrence state (h) kept f32; Xi stored f32 (bf16 fallback if ws too small).

#define TT 256
#define BB 256
#define DD 512
#define AA 32
#define MM (TT * BB)   // 65536 rows
#define RB 16          // rows per block in big GEMMs

// ---------------- fused GEMM(512x512) + bias + LayerNorm + ReLU ----------------
// One block owns RB full output rows (needed for LN row stats). In-place safe:
// each output row depends only on the same input row, staged to LDS first.
__global__ __launch_bounds__(256) void gemm_ln_relu_k(
    const float* __restrict__ X, float* __restrict__ Y,
    const float* __restrict__ W, const float* __restrict__ bias,
    const float* __restrict__ gamma, const float* __restrict__ beta)
{
    __shared__ float xs[RB][DD];
    __shared__ float s_mu[RB], s_rs[RB];
    const int tid = threadIdx.x;
    const long row0 = (long)blockIdx.x * RB;

    for (int idx = tid; idx < RB * DD; idx += 256) {
        int r = idx >> 9, c = idx & 511;
        xs[r][c] = X[(row0 + r) * DD + c];
    }
    __syncthreads();

    const int j0 = tid * 2;
    float acc0[RB], acc1[RB];
#pragma unroll
    for (int r = 0; r < RB; r++) { acc0[r] = 0.f; acc1[r] = 0.f; }

    for (int k = 0; k < DD; k += 4) {
        float2 w0 = *(const float2*)(W + (size_t)(k + 0) * DD + j0);
        float2 w1 = *(const float2*)(W + (size_t)(k + 1) * DD + j0);
        float2 w2 = *(const float2*)(W + (size_t)(k + 2) * DD + j0);
        float2 w3 = *(const float2*)(W + (size_t)(k + 3) * DD + j0);
#pragma unroll
        for (int r = 0; r < RB; r++) {
            float4 xv = *(const float4*)(&xs[r][k]);
            acc0[r] = fmaf(xv.x, w0.x, acc0[r]);
            acc1[r] = fmaf(xv.x, w0.y, acc1[r]);
            acc0[r] = fmaf(xv.y, w1.x, acc0[r]);
            acc1[r] = fmaf(xv.y, w1.y, acc1[r]);
            acc0[r] = fmaf(xv.z, w2.x, acc0[r]);
            acc1[r] = fmaf(xv.z, w2.y, acc1[r]);
            acc0[r] = fmaf(xv.w, w3.x, acc0[r]);
            acc1[r] = fmaf(xv.w, w3.y, acc1[r]);
        }
    }
    __syncthreads();  // all threads done reading xs; reuse it for pre-LN staging

    float b0 = bias[j0], b1 = bias[j0 + 1];
#pragma unroll
    for (int r = 0; r < RB; r++) {
        xs[r][j0]     = acc0[r] + b0;
        xs[r][j0 + 1] = acc1[r] + b1;
    }
    __syncthreads();

    {   // 16 threads per row compute mean / rstd
        int r = tid >> 4, l = tid & 15;
        float s = 0.f, s2 = 0.f;
        for (int c = l; c < DD; c += 16) { float v = xs[r][c]; s += v; s2 += v * v; }
#pragma unroll
        for (int off = 8; off > 0; off >>= 1) {
            s  += __shfl_down(s,  off, 16);
            s2 += __shfl_down(s2, off, 16);
        }
        if (l == 0) {
            float mu  = s * (1.f / (float)DD);
            float var = s2 * (1.f / (float)DD) - mu * mu;
            s_mu[r] = mu;
            s_rs[r] = rsqrtf(var + 1e-6f);
        }
    }
    __syncthreads();

    for (int idx = tid; idx < RB * DD; idx += 256) {
        int r = idx >> 9, c = idx & 511;
        float v = (xs[r][c] - s_mu[r]) * s_rs[r] * gamma[c] + beta[c];
        Y[(row0 + r) * DD + c] = fmaxf(v, 0.f);
    }
}

// ---------------- Xi = E @ Wi[g] + bi[g], g = blockIdx.y ----------------
__global__ __launch_bounds__(256) void gemm_xi_k(
    const float* __restrict__ X, const float* __restrict__ Wi,
    const float* __restrict__ bi, float* __restrict__ xi_f32,
    __hip_bfloat16* __restrict__ xi_bf16, int use_bf16)
{
    __shared__ float xs[RB][DD];
    const int tid = threadIdx.x;
    const long row0 = (long)blockIdx.x * RB;

    for (int idx = tid; idx < RB * DD; idx += 256) {
        int r = idx >> 9, c = idx & 511;
        xs[r][c] = X[(row0 + r) * DD + c];
    }
    __syncthreads();

    const float* W = Wi + (size_t)blockIdx.y * DD * DD;
    const int j0 = tid * 2;
    float acc0[RB], acc1[RB];
#pragma unroll
    for (int r = 0; r < RB; r++) { acc0[r] = 0.f; acc1[r] = 0.f; }

    for (int k = 0; k < DD; k += 4) {
        float2 w0 = *(const float2*)(W + (size_t)(k + 0) * DD + j0);
        float2 w1 = *(const float2*)(W + (size_t)(k + 1) * DD + j0);
        float2 w2 = *(const float2*)(W + (size_t)(k + 2) * DD + j0);
        float2 w3 = *(const float2*)(W + (size_t)(k + 3) * DD + j0);
#pragma unroll
        for (int r = 0; r < RB; r++) {
            float4 xv = *(const float4*)(&xs[r][k]);
            acc0[r] = fmaf(xv.x, w0.x, acc0[r]);
            acc1[r] = fmaf(xv.x, w0.y, acc1[r]);
            acc0[r] = fmaf(xv.y, w1.x, acc0[r]);
            acc1[r] = fmaf(xv.y, w1.y, acc1[r]);
            acc0[r] = fmaf(xv.z, w2.x, acc0[r]);
            acc1[r] = fmaf(xv.z, w2.y, acc1[r]);
            acc0[r] = fmaf(xv.w, w3.x, acc0[r]);
            acc1[r] = fmaf(xv.w, w3.y, acc1[r]);
        }
    }

    const float* bz = bi + blockIdx.y * DD;
    float b0 = bz[j0], b1 = bz[j0 + 1];
    size_t colbase = (size_t)blockIdx.y * DD;
#pragma unroll
    for (int r = 0; r < RB; r++) {
        size_t o = (size_t)(row0 + r) * (3 * DD) + colbase + j0;
        float v0 = acc0[r] + b0, v1 = acc1[r] + b1;
        if (use_bf16) {
            xi_bf16[o]     = __float2bfloat16(v0);
            xi_bf16[o + 1] = __float2bfloat16(v1);
        } else {
            xi_f32[o]     = v0;
            xi_f32[o + 1] = v1;
        }
    }
}

// ---------------- one GRU timestep ----------------
// grid = (16,16): 16-row tiles x 32-col tiles. Block computes hr/hz/hn for its
// tile then the gate combine (element-wise in (b,j), so no cross-block comm).
__global__ __launch_bounds__(256) void gru_step_k(
    const float* __restrict__ h_in, float* __restrict__ h_out,
    const float* __restrict__ xi_f32, const __hip_bfloat16* __restrict__ xi_bf16,
    int use_bf16,
    const int* __restrict__ done_t,
    const float* __restrict__ Wh, const float* __restrict__ bhn,
    float* __restrict__ y_t)
{
    __shared__ float hs[16][DD];
    const int tid = threadIdx.x;
    const int row0 = blockIdx.x * 16;
    const int cb = blockIdx.y * 32;

    // stage reset-masked carry h' = done ? 0 : h
    for (int idx = tid; idx < 16 * DD; idx += 256) {
        int r = idx >> 9, c = idx & 511;
        int br = row0 + r;
        hs[r][c] = (done_t[br] != 0) ? 0.f : h_in[br * DD + c];
    }
    __syncthreads();

    const int c = cb + (tid & 31);
    const int r0 = (tid >> 5) * 2, r1 = r0 + 1;
    const float* W0 = Wh;
    const float* W1 = Wh + DD * DD;
    const float* W2 = Wh + 2 * DD * DD;

    float ar0 = 0.f, ar1 = 0.f, az0 = 0.f, az1 = 0.f, an0 = 0.f, an1 = 0.f;
    for (int k = 0; k < DD; k += 2) {
        float w0a = W0[(size_t)k * DD + c], w0b = W0[(size_t)(k + 1) * DD + c];
        float w1a = W1[(size_t)k * DD + c], w1b = W1[(size_t)(k + 1) * DD + c];
        float w2a = W2[(size_t)k * DD + c], w2b = W2[(size_t)(k + 1) * DD + c];
        float2 x0 = *(const float2*)&hs[r0][k];
        float2 x1 = *(const float2*)&hs[r1][k];
        ar0 = fmaf(x0.x, w0a, ar0); ar0 = fmaf(x0.y, w0b, ar0);
        az0 = fmaf(x0.x, w1a, az0); az0 = fmaf(x0.y, w1b, az0);
        an0 = fmaf(x0.x, w2a, an0); an0 = fmaf(x0.y, w2b, an0);
        ar1 = fmaf(x1.x, w0a, ar1); ar1 = fmaf(x1.y, w0b, ar1);
        az1 = fmaf(x1.x, w1a, az1); az1 = fmaf(x1.y, w1b, az1);
        an1 = fmaf(x1.x, w2a, an1); an1 = fmaf(x1.y, w2b, an1);
    }

    float bn = bhn[c];
#pragma unroll
    for (int rr = 0; rr < 2; rr++) {
        int r = rr ? r1 : r0;
        float ar = rr ? ar1 : ar0;
        float az = rr ? az1 : az0;
        float an = rr ? an1 : an0;
        int br = row0 + r;
        size_t xb = (size_t)br * (3 * DD) + c;
        float xr, xz, xn;
        if (use_bf16) {
            xr = __bfloat162float(xi_bf16[xb]);
            xz = __bfloat162float(xi_bf16[xb + DD]);
            xn = __bfloat162float(xi_bf16[xb + 2 * DD]);
        } else {
            xr = xi_f32[xb];
            xz = xi_f32[xb + DD];
            xn = xi_f32[xb + 2 * DD];
        }
        float rg = 1.f / (1.f + expf(-(xr + ar)));
        float zg = 1.f / (1.f + expf(-(xz + az)));
        float ng = tanhf(xn + rg * (an + bn));
        float hp = hs[r][c];
        float hn_ = (1.f - zg) * ng + zg * hp;
        h_out[br * DD + c] = hn_;
        y_t[br * DD + c] = hn_;
    }
}

// ---------------- logits = AM @ Wa + ba, avail masking ----------------
__global__ __launch_bounds__(256) void logits_k(
    const float* __restrict__ AM, const float* __restrict__ Wa,
    const float* __restrict__ ba, const int* __restrict__ avail,
    float* __restrict__ out)
{
    __shared__ float xs[8][DD];
    const int tid = threadIdx.x;
    const long row0 = (long)blockIdx.x * 8;

    for (int idx = tid; idx < 8 * DD; idx += 256) {
        int r = idx >> 9, c = idx & 511;
        xs[r][c] = AM[(row0 + r) * DD + c];
    }
    __syncthreads();

    const int r = tid >> 5, a = tid & 31;
    float acc = 0.f;
    for (int k = 0; k < DD; k += 4) {
        float4 xv = *(const float4*)&xs[r][k];
        acc = fmaf(xv.x, Wa[(k + 0) * AA + a], acc);
        acc = fmaf(xv.y, Wa[(k + 1) * AA + a], acc);
        acc = fmaf(xv.z, Wa[(k + 2) * AA + a], acc);
        acc = fmaf(xv.w, Wa[(k + 3) * AA + a], acc);
    }
    long o = (row0 + r) * AA + a;
    float v = acc + ba[a];
    if (avail[o] == 0) v -= 1e10f;
    out[o] = v;
}

__global__ void copy_f32(const float* __restrict__ in, float* __restrict__ out, int n)
{
    int i = blockIdx.x * 256 + threadIdx.x;
    if (i < n) out[i] = in[i];
}

extern "C" void kernel_launch(void* const* d_in, const int* in_sizes, int n_in,
                              void* d_out, int out_size, void* d_ws, size_t ws_size,
                              hipStream_t stream)
{
    const float* hidden = (const float*)d_in[0];
    float*       obs    = (float*)d_in[1];   // reused in-place (harness restores inputs)
    const int*   dones  = (const int*)d_in[2];
    const int*   avail  = (const int*)d_in[3];
    const float* Wm     = (const float*)d_in[4];
    const float* bm     = (const float*)d_in[5];
    const float* lns    = (const float*)d_in[6];
    const float* lnb    = (const float*)d_in[7];
    const float* Wi     = (const float*)d_in[8];
    const float* bi     = (const float*)d_in[9];
    const float* Wh     = (const float*)d_in[10];
    const float* bhn    = (const float*)d_in[11];
    const float* Wo     = (const float*)d_in[12];
    const float* bo     = (const float*)d_in[13];
    const float* ln2s   = (const float*)d_in[14];
    const float* ln2b   = (const float*)d_in[15];
    const float* Wa     = (const float*)d_in[16];
    const float* ba     = (const float*)d_in[17];
    float* out = (float*)d_out;

    const size_t XI_F32_BYTES = (size_t)MM * 3 * DD * 4;
    const size_t H_BYTES      = (size_t)BB * DD * 4;
    int use_bf16 = (ws_size < XI_F32_BYTES + 2 * H_BYTES) ? 1 : 0;

    char* wsc = (char*)d_ws;
    float*          xi_f32  = (float*)wsc;
    __hip_bfloat16* xi_bf16 = (__hip_bfloat16*)wsc;
    size_t xi_bytes = use_bf16 ? XI_F32_BYTES / 2 : XI_F32_BYTES;
    float* h0 = (float*)(wsc + xi_bytes);
    float* h1 = (float*)(wsc + xi_bytes + H_BYTES);

    // init carry
    copy_f32<<<dim3(512), dim3(256), 0, stream>>>(hidden, h0, BB * DD);

    // MLP encoder, in-place on obs
    for (int l = 0; l < 3; l++) {
        gemm_ln_relu_k<<<dim3(MM / RB), dim3(256), 0, stream>>>(
            obs, obs, Wm + (size_t)l * DD * DD, bm + l * DD, lns + l * DD, lnb + l * DD);
    }

    // Xi = E @ Wi + bi (all gates, all timesteps)
    gemm_xi_k<<<dim3(MM / RB, 3), dim3(256), 0, stream>>>(
        obs, Wi, bi, xi_f32, xi_bf16, use_bf16);

    // sequential GRU; y written into obs buffer (E is dead now)
    float* hb[2] = { h0, h1 };
    int cur = 0;
    for (int t = 0; t < TT; t++) {
        gru_step_k<<<dim3(16, 16), dim3(256), 0, stream>>>(
            hb[cur], hb[cur ^ 1],
            xi_f32 + (size_t)t * BB * 3 * DD,
            xi_bf16 + (size_t)t * BB * 3 * DD,
            use_bf16,
            dones + t * BB, Wh, bhn,
            obs + (size_t)t * BB * DD);
        cur ^= 1;
    }

    // actor head LN block, in-place on obs (y -> am)
    gemm_ln_relu_k<<<dim3(MM / RB), dim3(256), 0, stream>>>(
        obs, obs, Wo, bo, ln2s, ln2b);

    // logits + masking
    logits_k<<<dim3(MM / 8), dim3(256), 0, stream>>>(
        obs, Wa, ba, avail, out + BB * DD);

    // final hidden
    copy_f32<<<dim3(512), dim3(256), 0, stream>>>(hb[cur], out, BB * DD);
}

// Round 2
// 4919.870 us; speedup vs baseline: 2.3028x; 2.3028x over previous
//
#include <hip/hip_runtime.h>
#include <hip/hip_bf16.h>
#include <math.h>

// PPOActorRNN on MI355X — round 2: bf16 MFMA everywhere.
// T=256 B=256 D=512 A=32. All GEMMs K=512, 16x16x32 bf16 MFMA,
// XOR-swizzled LDS staging (conflict-free ds_read_b128 / ds_write_b128).
//
// Pipeline:
//   prep: transpose+cvt all weights to bf16 [n][k] in ws
//   L1: obs(f32) @ WmT0 -> P(bf16); LN+ReLU in-place
//   L2: P -> Q; LN. L3: Q -> P; LN.  (P = encoder output E)
//   per step t: HG[256x3072] = [E_t | mask(h)] @ [WiT(3)|WhT(3)] + [bi|0|bhn]
//               cols 0..1535 use A=E_t (bf16), cols 1536..3071 use A=done?0:h (f32)
//               gate_k: h in-place update, y_t -> Q (bf16)
//   head: Q -> P; LN.  logits: P @ Wa + ba, avail mask -> out[131072:]
//   hidden out: copy h -> out[0:131072]

#define TT 256
#define BB 256
#define DD 512
#define ACT 32
#define MM (TT*TT)  // 65536 rows (T*B)

typedef short bf16x8 __attribute__((ext_vector_type(8)));
typedef short bf16x4_t __attribute__((ext_vector_type(4)));
typedef float f32x4 __attribute__((ext_vector_type(4)));
typedef unsigned short u16;

__device__ inline u16 f2bf(float f) {              // RNE f32 -> bf16
    unsigned int u = __float_as_uint(f);
    u += 0x7fffu + ((u >> 16) & 1u);
    return (u16)(u >> 16);
}
__device__ inline float bf2f(u16 h) { return __uint_as_float(((unsigned int)h) << 16); }

// ---------------- weight transpose + cvt: out[n][k] = bf16(in[k][n]), 512x512 ----
__global__ __launch_bounds__(256) void transpose_cvt_k(
    const float* __restrict__ in, u16* __restrict__ out)
{
    __shared__ float tile[32][33];
    const int c = threadIdx.x & 31;
    const int r0 = threadIdx.x >> 5;          // 0..7
    const int bx = blockIdx.x, by = blockIdx.y;
#pragma unroll
    for (int p = 0; p < 4; p++) {
        int r = r0 + p * 8;
        tile[r][c] = in[(size_t)(by * 32 + r) * DD + bx * 32 + c];
    }
    __syncthreads();
#pragma unroll
    for (int p = 0; p < 4; p++) {
        int r = r0 + p * 8;
        out[(size_t)(bx * 32 + r) * DD + by * 32 + c] = f2bf(tile[c][r]);
    }
}

// ---------------- MFMA GEMM: C[M x N](bf16) = A[M x 512] @ Bt^T + bias ----------
// Bt is [N][512] bf16 (transposed weights). Tile 128x128, BK=64, 4 waves (2x2),
// each wave 4x4 tiles of 16x16. LDS XOR-swizzle: 8-elem group j of row r stored
// at group (j ^ (r&7)) -> conflict-free b128 on both write and frag-read.
template<bool AF32>
__global__ __launch_bounds__(256) void gemm_bf16_k(
    const void* __restrict__ Aptr, const u16* __restrict__ Bt,
    const float* __restrict__ bias, u16* __restrict__ C, int N)
{
    __shared__ u16 As[128 * 64];
    __shared__ u16 Bs[128 * 64];
    const int tid = threadIdx.x;
    const int row0 = blockIdx.x * 128;
    const int col0 = blockIdx.y * 128;
    const int lane = tid & 63, wid = tid >> 6;
    const int wr = wid >> 1, wc = wid & 1;
    const int lm = lane & 15, lq = lane >> 4;

    f32x4 acc[4][4];
#pragma unroll
    for (int i = 0; i < 4; i++)
#pragma unroll
        for (int j = 0; j < 4; j++) acc[i][j] = (f32x4){0.f, 0.f, 0.f, 0.f};

    for (int kc = 0; kc < 8; kc++) {
        const int k0 = kc * 64;
#pragma unroll
        for (int p = 0; p < 4; p++) {          // stage A: 128 x 64
            int g = p * 256 + tid;
            int row = g >> 3, j = g & 7;
            bf16x8 v;
            if (AF32) {
                const float* s = (const float*)Aptr + (size_t)(row0 + row) * DD + k0 + j * 8;
                float4 a0 = *(const float4*)s;
                float4 a1 = *(const float4*)(s + 4);
                v[0] = (short)f2bf(a0.x); v[1] = (short)f2bf(a0.y);
                v[2] = (short)f2bf(a0.z); v[3] = (short)f2bf(a0.w);
                v[4] = (short)f2bf(a1.x); v[5] = (short)f2bf(a1.y);
                v[6] = (short)f2bf(a1.z); v[7] = (short)f2bf(a1.w);
            } else {
                v = *(const bf16x8*)((const u16*)Aptr + (size_t)(row0 + row) * DD + k0 + j * 8);
            }
            *(bf16x8*)(As + row * 64 + ((j ^ (row & 7)) << 3)) = v;
        }
#pragma unroll
        for (int p = 0; p < 4; p++) {          // stage B: 128 x 64
            int g = p * 256 + tid;
            int n = g >> 3, j = g & 7;
            bf16x8 v = *(const bf16x8*)(Bt + (size_t)(col0 + n) * DD + k0 + j * 8);
            *(bf16x8*)(Bs + n * 64 + ((j ^ (n & 7)) << 3)) = v;
        }
        __syncthreads();
#pragma unroll
        for (int ks = 0; ks < 2; ks++) {
            bf16x8 af[4], bfr[4];
#pragma unroll
            for (int i = 0; i < 4; i++) {
                int row = wr * 64 + i * 16 + lm;
                af[i] = *(const bf16x8*)(As + row * 64 + (((ks * 4 + lq) ^ (row & 7)) << 3));
            }
#pragma unroll
            for (int j = 0; j < 4; j++) {
                int n = wc * 64 + j * 16 + lm;
                bfr[j] = *(const bf16x8*)(Bs + n * 64 + (((ks * 4 + lq) ^ (n & 7)) << 3));
            }
#pragma unroll
            for (int i = 0; i < 4; i++)
#pragma unroll
                for (int j = 0; j < 4; j++)
                    acc[i][j] = __builtin_amdgcn_mfma_f32_16x16x32_bf16(af[i], bfr[j], acc[i][j], 0, 0, 0);
        }
        __syncthreads();
    }
    // epilogue: C/D layout col=lane&15, row=(lane>>4)*4+reg
#pragma unroll
    for (int j = 0; j < 4; j++) {
        int col = col0 + wc * 64 + j * 16 + lm;
        float bj = bias[col];
#pragma unroll
        for (int i = 0; i < 4; i++) {
            int rb = row0 + wr * 64 + i * 16 + lq * 4;
#pragma unroll
            for (int r = 0; r < 4; r++)
                C[(size_t)(rb + r) * N + col] = f2bf(acc[i][j][r] + bj);
        }
    }
}

// ---------------- GRU step GEMM: HG[256 x 3072] ----------------
// cols [0,1536):   E_t @ WiT(g)  + bi           (A = E_t, bf16)
// cols [1536,3072): h' @ WhT(g)  + (0|0|bhn)    (A = done?0:h, f32->bf16)
// Tile 64x128 (NI=2), same swizzle scheme.
__global__ __launch_bounds__(256) void gru_gemm_k(
    const u16* __restrict__ Et, const float* __restrict__ h,
    const int* __restrict__ done_t, const u16* __restrict__ BgT,
    const float* __restrict__ bi, const float* __restrict__ bhn,
    float* __restrict__ HG)
{
    __shared__ u16 As[64 * 64];
    __shared__ u16 Bs[128 * 64];
    const int tid = threadIdx.x;
    const int row0 = blockIdx.x * 64;
    const int col0 = blockIdx.y * 128;
    const bool isH = (col0 >= 1536);
    const int lane = tid & 63, wid = tid >> 6;
    const int wr = wid >> 1, wc = wid & 1;
    const int lm = lane & 15, lq = lane >> 4;

    f32x4 acc[2][4];
#pragma unroll
    for (int i = 0; i < 2; i++)
#pragma unroll
        for (int j = 0; j < 4; j++) acc[i][j] = (f32x4){0.f, 0.f, 0.f, 0.f};

    for (int kc = 0; kc < 8; kc++) {
        const int k0 = kc * 64;
#pragma unroll
        for (int p = 0; p < 2; p++) {          // stage A: 64 x 64
            int g = p * 256 + tid;
            int row = g >> 3, j = g & 7;
            bf16x8 v;
            if (!isH) {
                v = *(const bf16x8*)(Et + (size_t)(row0 + row) * DD + k0 + j * 8);
            } else {
                const float* s = h + (size_t)(row0 + row) * DD + k0 + j * 8;
                float m = (done_t[row0 + row] != 0) ? 0.f : 1.f;
                float4 a0 = *(const float4*)s;
                float4 a1 = *(const float4*)(s + 4);
                v[0] = (short)f2bf(a0.x * m); v[1] = (short)f2bf(a0.y * m);
                v[2] = (short)f2bf(a0.z * m); v[3] = (short)f2bf(a0.w * m);
                v[4] = (short)f2bf(a1.x * m); v[5] = (short)f2bf(a1.y * m);
                v[6] = (short)f2bf(a1.z * m); v[7] = (short)f2bf(a1.w * m);
            }
            *(bf16x8*)(As + row * 64 + ((j ^ (row & 7)) << 3)) = v;
        }
#pragma unroll
        for (int p = 0; p < 4; p++) {          // stage B: 128 x 64
            int g = p * 256 + tid;
            int n = g >> 3, j = g & 7;
            bf16x8 v = *(const bf16x8*)(BgT + (size_t)(col0 + n) * DD + k0 + j * 8);
            *(bf16x8*)(Bs + n * 64 + ((j ^ (n & 7)) << 3)) = v;
        }
        __syncthreads();
#pragma unroll
        for (int ks = 0; ks < 2; ks++) {
            bf16x8 af[2], bfr[4];
#pragma unroll
            for (int i = 0; i < 2; i++) {
                int row = wr * 32 + i * 16 + lm;
                af[i] = *(const bf16x8*)(As + row * 64 + (((ks * 4 + lq) ^ (row & 7)) << 3));
            }
#pragma unroll
            for (int j = 0; j < 4; j++) {
                int n = wc * 64 + j * 16 + lm;
                bfr[j] = *(const bf16x8*)(Bs + n * 64 + (((ks * 4 + lq) ^ (n & 7)) << 3));
            }
#pragma unroll
            for (int i = 0; i < 2; i++)
#pragma unroll
                for (int j = 0; j < 4; j++)
                    acc[i][j] = __builtin_amdgcn_mfma_f32_16x16x32_bf16(af[i], bfr[j], acc[i][j], 0, 0, 0);
        }
        __syncthreads();
    }
#pragma unroll
    for (int j = 0; j < 4; j++) {
        int col = col0 + wc * 64 + j * 16 + lm;
        float bj = (col < 1536) ? bi[col] : ((col >= 2560) ? bhn[col - 2560] : 0.f);
#pragma unroll
        for (int i = 0; i < 2; i++) {
            int rb = row0 + wr * 32 + i * 16 + lq * 4;
#pragma unroll
            for (int r = 0; r < 4; r++)
                HG[(size_t)(rb + r) * 3072 + col] = acc[i][j][r] + bj;
        }
    }
}

// ---------------- gate combine: h in-place, y_t bf16 ----------------
__device__ inline float gate1(float xr, float xz, float xn,
                              float hr, float hz, float hn, float hp)
{
    float r = 1.f / (1.f + __expf(-(xr + hr)));
    float z = 1.f / (1.f + __expf(-(xz + hz)));
    float n = tanhf(xn + r * hn);        // bi[2] in xn, bhn in hn already
    return (1.f - z) * n + z * hp;
}

__global__ __launch_bounds__(256) void gate_k(
    const float* __restrict__ HG, float* __restrict__ h,
    const int* __restrict__ done_t, u16* __restrict__ y)
{
    const int idx = blockIdx.x * 256 + threadIdx.x;
    const int b = idx >> 7;
    const int n0 = (idx & 127) * 4;
    const float* base = HG + (size_t)b * 3072 + n0;
    float4 xr = *(const float4*)(base);
    float4 xz = *(const float4*)(base + 512);
    float4 xn = *(const float4*)(base + 1024);
    float4 hr = *(const float4*)(base + 1536);
    float4 hz = *(const float4*)(base + 2048);
    float4 hn = *(const float4*)(base + 2560);
    float4 hv = *(const float4*)(h + (size_t)b * DD + n0);
    const bool d = done_t[b] != 0;
    float o0 = gate1(xr.x, xz.x, xn.x, hr.x, hz.x, hn.x, d ? 0.f : hv.x);
    float o1 = gate1(xr.y, xz.y, xn.y, hr.y, hz.y, hn.y, d ? 0.f : hv.y);
    float o2 = gate1(xr.z, xz.z, xn.z, hr.z, hz.z, hn.z, d ? 0.f : hv.z);
    float o3 = gate1(xr.w, xz.w, xn.w, hr.w, hz.w, hn.w, d ? 0.f : hv.w);
    *(float4*)(h + (size_t)b * DD + n0) = make_float4(o0, o1, o2, o3);
    bf16x4_t yo;
    yo[0] = (short)f2bf(o0); yo[1] = (short)f2bf(o1);
    yo[2] = (short)f2bf(o2); yo[3] = (short)f2bf(o3);
    *(bf16x4_t*)(y + (size_t)b * DD + n0) = yo;
}

// ---------------- LayerNorm + ReLU, in-place on bf16 [M x 512] ----------------
__global__ __launch_bounds__(256) void ln_relu_k(
    u16* __restrict__ X, const float* __restrict__ gamma, const float* __restrict__ beta)
{
    const int tid = threadIdx.x;
    const int lane = tid & 63;
    const size_t row = (size_t)blockIdx.x * 4 + (tid >> 6);
    const int c0 = lane * 8;
    u16* px = X + row * DD + c0;
    bf16x8 v = *(const bf16x8*)px;
    float f[8]; float s = 0.f, s2 = 0.f;
#pragma unroll
    for (int i = 0; i < 8; i++) { f[i] = bf2f((u16)v[i]); s += f[i]; s2 += f[i] * f[i]; }
#pragma unroll
    for (int off = 32; off; off >>= 1) { s += __shfl_xor(s, off); s2 += __shfl_xor(s2, off); }
    float mu = s * (1.f / (float)DD);
    float rs = rsqrtf(s2 * (1.f / (float)DD) - mu * mu + 1e-6f);
    float4 g0 = *(const float4*)(gamma + c0), g1 = *(const float4*)(gamma + c0 + 4);
    float4 b0 = *(const float4*)(beta + c0),  b1 = *(const float4*)(beta + c0 + 4);
    float gg[8] = {g0.x, g0.y, g0.z, g0.w, g1.x, g1.y, g1.z, g1.w};
    float bb[8] = {b0.x, b0.y, b0.z, b0.w, b1.x, b1.y, b1.z, b1.w};
    bf16x8 o;
#pragma unroll
    for (int i = 0; i < 8; i++) {
        float yv = (f[i] - mu) * rs * gg[i] + bb[i];
        o[i] = (short)f2bf(fmaxf(yv, 0.f));
    }
    *(bf16x8*)px = o;
}

// ---------------- logits = AM(bf16) @ Wa + ba, avail mask ----------------
__global__ __launch_bounds__(256) void logits_k(
    const u16* __restrict__ AM, const float* __restrict__ Wa,
    const float* __restrict__ ba, const int* __restrict__ avail,
    float* __restrict__ out)
{
    __shared__ float xs[8][DD];
    const int tid = threadIdx.x;
    const size_t row0 = (size_t)blockIdx.x * 8;
    for (int g = tid; g < 8 * 64; g += 256) {
        int r = g >> 6, c8 = (g & 63) * 8;
        bf16x8 v = *(const bf16x8*)(AM + (row0 + r) * DD + c8);
#pragma unroll
        for (int i = 0; i < 8; i++) xs[r][c8 + i] = bf2f((u16)v[i]);
    }
    __syncthreads();
    const int r = tid >> 5, a = tid & 31;
    float acc = 0.f;
    for (int k = 0; k < DD; k += 4) {
        float4 xv = *(const float4*)&xs[r][k];
        acc = fmaf(xv.x, Wa[(k + 0) * ACT + a], acc);
        acc = fmaf(xv.y, Wa[(k + 1) * ACT + a], acc);
        acc = fmaf(xv.z, Wa[(k + 2) * ACT + a], acc);
        acc = fmaf(xv.w, Wa[(k + 3) * ACT + a], acc);
    }
    size_t o = (row0 + r) * ACT + a;
    float v = acc + ba[a];
    if (avail[o] == 0) v -= 1e10f;
    out[o] = v;
}

__global__ void copy_f32(const float* __restrict__ in, float* __restrict__ out, int n)
{
    int i = blockIdx.x * 256 + threadIdx.x;
    if (i < n) out[i] = in[i];
}

extern "C" void kernel_launch(void* const* d_in, const int* in_sizes, int n_in,
                              void* d_out, int out_size, void* d_ws, size_t ws_size,
                              hipStream_t stream)
{
    const float* hidden = (const float*)d_in[0];
    const float* obs    = (const float*)d_in[1];
    const int*   dones  = (const int*)d_in[2];
    const int*   avail  = (const int*)d_in[3];
    const float* Wm     = (const float*)d_in[4];
    const float* bm     = (const float*)d_in[5];
    const float* lns    = (const float*)d_in[6];
    const float* lnb    = (const float*)d_in[7];
    const float* Wi     = (const float*)d_in[8];
    const float* bi     = (const float*)d_in[9];
    const float* Wh     = (const float*)d_in[10];
    const float* bhn    = (const float*)d_in[11];
    const float* Wo     = (const float*)d_in[12];
    const float* bo     = (const float*)d_in[13];
    const float* ln2s   = (const float*)d_in[14];
    const float* ln2b   = (const float*)d_in[15];
    const float* Wa     = (const float*)d_in[16];
    const float* ba     = (const float*)d_in[17];
    float* out = (float*)d_out;

    // workspace layout (~143 MB)
    char* w = (char*)d_ws;
    u16* WmT = (u16*)w;  w += (size_t)3 * DD * DD * 2;
    u16* WoT = (u16*)w;  w += (size_t)DD * DD * 2;
    u16* BgT = (u16*)w;  w += (size_t)6 * DD * DD * 2;   // [WiT0..2 | WhT0..2] = [3072][512]
    float* HG = (float*)w;  w += (size_t)BB * 3072 * 4;
    float* h  = (float*)w;  w += (size_t)BB * DD * 4;
    u16* P = (u16*)w;  w += (size_t)MM * DD * 2;
    u16* Q = (u16*)w;

    dim3 tgrid(16, 16);
    for (int l = 0; l < 3; l++)
        transpose_cvt_k<<<tgrid, 256, 0, stream>>>(Wm + (size_t)l * DD * DD, WmT + (size_t)l * DD * DD);
    transpose_cvt_k<<<tgrid, 256, 0, stream>>>(Wo, WoT);
    for (int g = 0; g < 3; g++)
        transpose_cvt_k<<<tgrid, 256, 0, stream>>>(Wi + (size_t)g * DD * DD, BgT + (size_t)g * DD * DD);
    for (int g = 0; g < 3; g++)
        transpose_cvt_k<<<tgrid, 256, 0, stream>>>(Wh + (size_t)g * DD * DD, BgT + (size_t)(3 + g) * DD * DD);
    copy_f32<<<dim3(512), dim3(256), 0, stream>>>(hidden, h, BB * DD);

    // MLP encoder
    gemm_bf16_k<true><<<dim3(MM / 128, 4), 256, 0, stream>>>(obs, WmT, bm, P, DD);
    ln_relu_k<<<dim3(MM / 4), 256, 0, stream>>>(P, lns, lnb);
    gemm_bf16_k<false><<<dim3(MM / 128, 4), 256, 0, stream>>>(P, WmT + (size_t)DD * DD, bm + DD, Q, DD);
    ln_relu_k<<<dim3(MM / 4), 256, 0, stream>>>(Q, lns + DD, lnb + DD);
    gemm_bf16_k<false><<<dim3(MM / 128, 4), 256, 0, stream>>>(Q, WmT + (size_t)2 * DD * DD, bm + 2 * DD, P, DD);
    ln_relu_k<<<dim3(MM / 4), 256, 0, stream>>>(P, lns + 2 * DD, lnb + 2 * DD);

    // GRU scan: P holds E; y goes into Q
    for (int t = 0; t < TT; t++) {
        gru_gemm_k<<<dim3(BB / 64, 24), 256, 0, stream>>>(
            P + (size_t)t * BB * DD, h, dones + t * BB, BgT, bi, bhn, HG);
        gate_k<<<dim3(BB * DD / 1024), 256, 0, stream>>>(
            HG, h, dones + t * BB, Q + (size_t)t * BB * DD);
    }

    // actor head
    gemm_bf16_k<false><<<dim3(MM / 128, 4), 256, 0, stream>>>(Q, WoT, bo, P, DD);
    ln_relu_k<<<dim3(MM / 4), 256, 0, stream>>>(P, ln2s, ln2b);
    logits_k<<<dim3(MM / 8), 256, 0, stream>>>(P, Wa, ba, avail, out + BB * DD);
    copy_f32<<<dim3(512), dim3(256), 0, stream>>>(h, out, BB * DD);
}

// Round 3
// 4344.883 us; speedup vs baseline: 2.6075x; 1.1323x over previous
//
#include <hip/hip_runtime.h>
#include <hip/hip_cooperative_groups.h>
#include <hip/hip_bf16.h>
#include <math.h>

namespace cg = cooperative_groups;

// PPOActorRNN on MI355X — round 3: depth-parallel GRU (done-segmentation).
// T=256 B=256 D=512 A=32.
//   prep:   transpose+cvt weights to bf16 [n][k]; Wstk[1536][1024] = [Wi_g ; Wh_g] stacked per gate
//   lists:  depth(t,b) = steps since last reset; per-depth compacted position lists
//   encoder: obs ->P ->Y ->P (3x MFMA GEMM + LN+ReLU), E ends in P
//   GRU:    ONE cooperative kernel; for d = 0..maxd: all positions at depth d in parallel.
//           job = 64 rows x 32-col gate slice; wave0=r, wave1=z, wave2=xn/hn (K-split);
//           gates combined in-block via LDS; Y[pos] = h. grid.sync() per depth.
//   head:   Y -> P (GEMM+LN), logits -> out.  hidden out copied inside coop kernel.

#define TTT 256
#define BBB 256
#define DDD 512
#define ACT 32
#define MMM (TTT*BBB)

typedef short bf16x8 __attribute__((ext_vector_type(8)));
typedef float f32x4 __attribute__((ext_vector_type(4)));
typedef unsigned short u16;

__device__ inline u16 f2bf(float f) {
    unsigned int u = __float_as_uint(f);
    u += 0x7fffu + ((u >> 16) & 1u);
    return (u16)(u >> 16);
}
__device__ inline float bf2f(u16 h) { return __uint_as_float(((unsigned int)h) << 16); }

// ---------------- transpose + cvt: out[n*ostride + k] = bf16(in[k*512 + n]) ----
__global__ __launch_bounds__(256) void transpose_cvt_k(
    const float* __restrict__ in, u16* __restrict__ out, int ostride)
{
    __shared__ float tile[32][33];
    const int c = threadIdx.x & 31;
    const int r0 = threadIdx.x >> 5;
    const int bx = blockIdx.x, by = blockIdx.y;
#pragma unroll
    for (int p = 0; p < 4; p++) {
        int r = r0 + p * 8;
        tile[r][c] = in[(size_t)(by * 32 + r) * DDD + bx * 32 + c];
    }
    __syncthreads();
#pragma unroll
    for (int p = 0; p < 4; p++) {
        int r = r0 + p * 8;
        out[(size_t)(bx * 32 + r) * ostride + by * 32 + c] = f2bf(tile[c][r]);
    }
}

// ---------------- MFMA GEMM (parallel phases): C[Mx512](bf16) = A @ Bt^T + bias ----
template<bool AF32>
__global__ __launch_bounds__(256) void gemm_bf16_k(
    const void* __restrict__ Aptr, const u16* __restrict__ Bt,
    const float* __restrict__ bias, u16* __restrict__ C, int N)
{
    __shared__ u16 As[128 * 64];
    __shared__ u16 Bs[128 * 64];
    const int tid = threadIdx.x;
    const int row0 = blockIdx.x * 128;
    const int col0 = blockIdx.y * 128;
    const int lane = tid & 63, wid = tid >> 6;
    const int wr = wid >> 1, wc = wid & 1;
    const int lm = lane & 15, lq = lane >> 4;

    f32x4 acc[4][4];
#pragma unroll
    for (int i = 0; i < 4; i++)
#pragma unroll
        for (int j = 0; j < 4; j++) acc[i][j] = (f32x4){0.f, 0.f, 0.f, 0.f};

    for (int kc = 0; kc < 8; kc++) {
        const int k0 = kc * 64;
#pragma unroll
        for (int p = 0; p < 4; p++) {
            int g = p * 256 + tid;
            int row = g >> 3, j = g & 7;
            bf16x8 v;
            if (AF32) {
                const float* s = (const float*)Aptr + (size_t)(row0 + row) * DDD + k0 + j * 8;
                float4 a0 = *(const float4*)s;
                float4 a1 = *(const float4*)(s + 4);
                v[0] = (short)f2bf(a0.x); v[1] = (short)f2bf(a0.y);
                v[2] = (short)f2bf(a0.z); v[3] = (short)f2bf(a0.w);
                v[4] = (short)f2bf(a1.x); v[5] = (short)f2bf(a1.y);
                v[6] = (short)f2bf(a1.z); v[7] = (short)f2bf(a1.w);
            } else {
                v = *(const bf16x8*)((const u16*)Aptr + (size_t)(row0 + row) * DDD + k0 + j * 8);
            }
            *(bf16x8*)(As + row * 64 + ((j ^ (row & 7)) << 3)) = v;
        }
#pragma unroll
        for (int p = 0; p < 4; p++) {
            int g = p * 256 + tid;
            int n = g >> 3, j = g & 7;
            bf16x8 v = *(const bf16x8*)(Bt + (size_t)(col0 + n) * DDD + k0 + j * 8);
            *(bf16x8*)(Bs + n * 64 + ((j ^ (n & 7)) << 3)) = v;
        }
        __syncthreads();
#pragma unroll
        for (int ks = 0; ks < 2; ks++) {
            bf16x8 af[4], bfr[4];
#pragma unroll
            for (int i = 0; i < 4; i++) {
                int row = wr * 64 + i * 16 + lm;
                af[i] = *(const bf16x8*)(As + row * 64 + (((ks * 4 + lq) ^ (row & 7)) << 3));
            }
#pragma unroll
            for (int j = 0; j < 4; j++) {
                int n = wc * 64 + j * 16 + lm;
                bfr[j] = *(const bf16x8*)(Bs + n * 64 + (((ks * 4 + lq) ^ (n & 7)) << 3));
            }
#pragma unroll
            for (int i = 0; i < 4; i++)
#pragma unroll
                for (int j = 0; j < 4; j++)
                    acc[i][j] = __builtin_amdgcn_mfma_f32_16x16x32_bf16(af[i], bfr[j], acc[i][j], 0, 0, 0);
        }
        __syncthreads();
    }
#pragma unroll
    for (int j = 0; j < 4; j++) {
        int col = col0 + wc * 64 + j * 16 + lm;
        float bj = bias[col];
#pragma unroll
        for (int i = 0; i < 4; i++) {
            int rb = row0 + wr * 64 + i * 16 + lq * 4;
#pragma unroll
            for (int r = 0; r < 4; r++)
                C[(size_t)(rb + r) * N + col] = f2bf(acc[i][j][r] + bj);
        }
    }
}

// ---------------- LayerNorm + ReLU in-place on bf16 [M x 512] ----------------
__global__ __launch_bounds__(256) void ln_relu_k(
    u16* __restrict__ X, const float* __restrict__ gamma, const float* __restrict__ beta)
{
    const int tid = threadIdx.x;
    const int lane = tid & 63;
    const size_t row = (size_t)blockIdx.x * 4 + (tid >> 6);
    const int c0 = lane * 8;
    u16* px = X + row * DDD + c0;
    bf16x8 v = *(const bf16x8*)px;
    float f[8]; float s = 0.f, s2 = 0.f;
#pragma unroll
    for (int i = 0; i < 8; i++) { f[i] = bf2f((u16)v[i]); s += f[i]; s2 += f[i] * f[i]; }
#pragma unroll
    for (int off = 32; off; off >>= 1) { s += __shfl_xor(s, off); s2 += __shfl_xor(s2, off); }
    float mu = s * (1.f / (float)DDD);
    float rs = rsqrtf(s2 * (1.f / (float)DDD) - mu * mu + 1e-6f);
    float4 g0 = *(const float4*)(gamma + c0), g1 = *(const float4*)(gamma + c0 + 4);
    float4 b0 = *(const float4*)(beta + c0),  b1 = *(const float4*)(beta + c0 + 4);
    float gg[8] = {g0.x, g0.y, g0.z, g0.w, g1.x, g1.y, g1.z, g1.w};
    float bb[8] = {b0.x, b0.y, b0.z, b0.w, b1.x, b1.y, b1.z, b1.w};
    bf16x8 o;
#pragma unroll
    for (int i = 0; i < 8; i++) {
        float yv = (f[i] - mu) * rs * gg[i] + bb[i];
        o[i] = (short)f2bf(fmaxf(yv, 0.f));
    }
    *(bf16x8*)px = o;
}

// ---------------- logits ----------------
__global__ __launch_bounds__(256) void logits_k(
    const u16* __restrict__ AM, const float* __restrict__ Wa,
    const float* __restrict__ ba, const int* __restrict__ avail,
    float* __restrict__ out)
{
    __shared__ float xs[8][DDD];
    const int tid = threadIdx.x;
    const size_t row0 = (size_t)blockIdx.x * 8;
    for (int g = tid; g < 8 * 64; g += 256) {
        int r = g >> 6, c8 = (g & 63) * 8;
        bf16x8 v = *(const bf16x8*)(AM + (row0 + r) * DDD + c8);
#pragma unroll
        for (int i = 0; i < 8; i++) xs[r][c8 + i] = bf2f((u16)v[i]);
    }
    __syncthreads();
    const int r = tid >> 5, a = tid & 31;
    float acc = 0.f;
    for (int k = 0; k < DDD; k += 4) {
        float4 xv = *(const float4*)&xs[r][k];
        acc = fmaf(xv.x, Wa[(k + 0) * ACT + a], acc);
        acc = fmaf(xv.y, Wa[(k + 1) * ACT + a], acc);
        acc = fmaf(xv.z, Wa[(k + 2) * ACT + a], acc);
        acc = fmaf(xv.w, Wa[(k + 3) * ACT + a], acc);
    }
    size_t o = (row0 + r) * ACT + a;
    float v = acc + ba[a];
    if (avail[o] == 0) v -= 1e10f;
    out[o] = v;
}

// ---------------- list building ----------------
__global__ void init_meta_k(int* meta)   // counts[256] | offs[256] | cursor[256] | maxd
{
    for (int i = threadIdx.x; i < 769; i += 256) meta[i] = 0;
}

__global__ void depth_build_k(const int* __restrict__ dones,
                              int* __restrict__ depthA, int* __restrict__ pidxA,
                              int* __restrict__ counts, int* __restrict__ maxd)
{
    const int b = threadIdx.x;   // 256 threads, 1 block
    int dprev = 0, mx = 0;
    for (int t = 0; t < TTT; t++) {
        int pos = t * BBB + b;
        int d, pi;
        if (dones[pos] != 0)       { d = 0; pi = -1; }
        else if (t == 0)           { d = 0; pi = -2 - b; }
        else                       { d = dprev + 1; pi = pos - BBB; }
        depthA[pos] = d; pidxA[pos] = pi;
        atomicAdd(&counts[d], 1);
        mx = max(mx, d);
        dprev = d;
    }
    atomicMax(maxd, mx);
}

__global__ void scan_k(const int* __restrict__ counts, int* __restrict__ offs)
{
    __shared__ int c[256];
    c[threadIdx.x] = counts[threadIdx.x];
    __syncthreads();
    if (threadIdx.x == 0) {
        int s = 0;
        for (int i = 0; i < 256; i++) { offs[i] = s; s += c[i]; }
    }
}

__global__ void scatter_k(const int* __restrict__ depthA, const int* __restrict__ offs,
                          int* __restrict__ cursor, int* __restrict__ list)
{
    int pos = blockIdx.x * 256 + threadIdx.x;
    int d = depthA[pos];
    int r = atomicAdd(&cursor[d], 1);
    list[offs[d] + r] = pos;
}

// ---------------- cooperative depth-scheduled GRU ----------------
// block = 192 thr (3 waves). job = (64-row tile) x (32-col gate slice, 16 panels).
// wave0: r_pre (K=1024 over [E|h]); wave1: z_pre; wave2: xn (k<512) / hn (k>=512).
template<bool YF32>
__global__ __launch_bounds__(192, 2) void gru_depth_k(
    const u16* __restrict__ E, const float* __restrict__ hidden,
    const u16* __restrict__ Wstk, const float* __restrict__ bi,
    const float* __restrict__ bhn,
    const int* __restrict__ list, const int* __restrict__ offs,
    const int* __restrict__ counts, const int* __restrict__ maxd,
    const int* __restrict__ pidxA,
    void* __restrict__ Yv, float* __restrict__ hid_out)
{
    cg::grid_group grid = cg::this_grid();
    __shared__ u16 AsBuf[64 * 256];          // 32 KB; reused as gate dump after K-loop
    __shared__ int posL[64], pidxL[64];
    u16* As = AsBuf;
    float* Gr = (float*)AsBuf;               // [64][32]
    float* Gz = Gr + 64 * 32;

    const int tid = threadIdx.x;
    const int w = tid / 64;
    const int lane = tid & 63;
    const int lm = lane & 15, lq = lane >> 4;

    const int MD = *maxd;
    for (int d = 0; d <= MD; d++) {
        const int nd = counts[d];
        const int off = offs[d];
        const int njobs = ((nd + 63) >> 6) * 16;
        for (int j = blockIdx.x; j < njobs; j += gridDim.x) {
            const int rt = j >> 4;
            const int panel = j & 15;
            if (tid < 64) {
                int idx = rt * 64 + tid;
                int p = (idx < nd) ? list[off + idx] : -1;
                posL[tid] = p;
                pidxL[tid] = (p >= 0) ? pidxA[p] : -1;
            }
            __syncthreads();

            f32x4 acc[4][2], acc2[4][2];
#pragma unroll
            for (int mt = 0; mt < 4; mt++)
#pragma unroll
                for (int nt = 0; nt < 2; nt++) {
                    acc[mt][nt] = (f32x4){0.f, 0.f, 0.f, 0.f};
                    acc2[mt][nt] = (f32x4){0.f, 0.f, 0.f, 0.f};
                }

            for (int kc = 0; kc < 4; kc++) {
                // stage A chunk: 64 rows x 256 (k-global = kc*256 ..)
                for (int g = tid; g < 2048; g += 192) {
                    int row = g >> 5, jg = g & 31;
                    int kglob = kc * 256 + jg * 8;
                    bf16x8 v = (bf16x8){0, 0, 0, 0, 0, 0, 0, 0};
                    int p = posL[row];
                    if (p >= 0) {
                        if (kglob < 512) {
                            v = *(const bf16x8*)(E + (size_t)p * DDD + kglob);
                        } else {
                            int k2 = kglob - 512;
                            int pi = pidxL[row];
                            if (pi >= 0) {
                                if (YF32) {
                                    const float* s = (const float*)Yv + (size_t)pi * DDD + k2;
                                    float4 a0 = *(const float4*)s;
                                    float4 a1 = *(const float4*)(s + 4);
                                    v[0] = (short)f2bf(a0.x); v[1] = (short)f2bf(a0.y);
                                    v[2] = (short)f2bf(a0.z); v[3] = (short)f2bf(a0.w);
                                    v[4] = (short)f2bf(a1.x); v[5] = (short)f2bf(a1.y);
                                    v[6] = (short)f2bf(a1.z); v[7] = (short)f2bf(a1.w);
                                } else {
                                    v = *(const bf16x8*)((const u16*)Yv + (size_t)pi * DDD + k2);
                                }
                            } else if (pi <= -2) {
                                const float* s = hidden + (size_t)(-pi - 2) * DDD + k2;
                                float4 a0 = *(const float4*)s;
                                float4 a1 = *(const float4*)(s + 4);
                                v[0] = (short)f2bf(a0.x); v[1] = (short)f2bf(a0.y);
                                v[2] = (short)f2bf(a0.z); v[3] = (short)f2bf(a0.w);
                                v[4] = (short)f2bf(a1.x); v[5] = (short)f2bf(a1.y);
                                v[6] = (short)f2bf(a1.z); v[7] = (short)f2bf(a1.w);
                            }
                        }
                    }
                    *(bf16x8*)(As + row * 256 + ((jg ^ (row & 31)) << 3)) = v;
                }
                __syncthreads();

                const int colbase = w * 512 + panel * 32;
                const bool second = (w == 2) && (kc >= 2);
#pragma unroll
                for (int s = 0; s < 8; s++) {
                    int kg = kc * 256 + s * 32;
                    bf16x8 bf0 = *(const bf16x8*)(Wstk + (size_t)(colbase + lm) * 1024 + kg + lq * 8);
                    bf16x8 bf1 = *(const bf16x8*)(Wstk + (size_t)(colbase + 16 + lm) * 1024 + kg + lq * 8);
#pragma unroll
                    for (int mt = 0; mt < 4; mt++) {
                        int row = mt * 16 + lm;
                        int jgr = s * 4 + lq;
                        bf16x8 af = *(const bf16x8*)(As + row * 256 + ((jgr ^ (row & 31)) << 3));
                        if (second) {
                            acc2[mt][0] = __builtin_amdgcn_mfma_f32_16x16x32_bf16(af, bf0, acc2[mt][0], 0, 0, 0);
                            acc2[mt][1] = __builtin_amdgcn_mfma_f32_16x16x32_bf16(af, bf1, acc2[mt][1], 0, 0, 0);
                        } else {
                            acc[mt][0] = __builtin_amdgcn_mfma_f32_16x16x32_bf16(af, bf0, acc[mt][0], 0, 0, 0);
                            acc[mt][1] = __builtin_amdgcn_mfma_f32_16x16x32_bf16(af, bf1, acc[mt][1], 0, 0, 0);
                        }
                    }
                }
                __syncthreads();
            }

            // dump r/z pre-activations (+input bias) into LDS
            if (w < 2) {
                float* G = w ? Gz : Gr;
                const float* bb = bi + w * 512 + panel * 32;
#pragma unroll
                for (int mt = 0; mt < 4; mt++)
#pragma unroll
                    for (int nt = 0; nt < 2; nt++)
#pragma unroll
                        for (int r = 0; r < 4; r++) {
                            int row = mt * 16 + lq * 4 + r;
                            int col = nt * 16 + lm;
                            G[row * 32 + col] = acc[mt][nt][r] + bb[col];
                        }
            }
            __syncthreads();

            // wave2: gate combine + Y write
            if (w == 2) {
                const float* bx = bi + 2 * 512 + panel * 32;
                const float* bh = bhn + panel * 32;
#pragma unroll
                for (int mt = 0; mt < 4; mt++)
#pragma unroll
                    for (int nt = 0; nt < 2; nt++)
#pragma unroll
                        for (int r = 0; r < 4; r++) {
                            int row = mt * 16 + lq * 4 + r;
                            int p = posL[row];
                            if (p < 0) continue;
                            int col = nt * 16 + lm;
                            int cglob = panel * 32 + col;
                            float rpre = Gr[row * 32 + col];
                            float zpre = Gz[row * 32 + col];
                            float xn = acc[mt][nt][r] + bx[col];
                            float hn = acc2[mt][nt][r] + bh[col];
                            float rg = 1.f / (1.f + __expf(-rpre));
                            float zg = 1.f / (1.f + __expf(-zpre));
                            float ng = tanhf(xn + rg * hn);
                            int pi = pidxL[row];
                            float hp = 0.f;
                            if (pi >= 0)
                                hp = YF32 ? ((const float*)Yv)[(size_t)pi * DDD + cglob]
                                          : bf2f(((const u16*)Yv)[(size_t)pi * DDD + cglob]);
                            else if (pi <= -2)
                                hp = hidden[(size_t)(-pi - 2) * DDD + cglob];
                            float hnew = (1.f - zg) * ng + zg * hp;
                            if (YF32) ((float*)Yv)[(size_t)p * DDD + cglob] = hnew;
                            else      ((u16*)Yv)[(size_t)p * DDD + cglob] = f2bf(hnew);
                        }
            }
            __syncthreads();
        }
        __threadfence();
        grid.sync();
    }

    // final hidden: out[b*512+c] = Y[(255*256+b)*512+c]
    for (int i = blockIdx.x * blockDim.x + tid; i < BBB * DDD; i += gridDim.x * blockDim.x) {
        int b = i >> 9, c = i & 511;
        size_t yi = (size_t)(65280 + b) * DDD + c;
        hid_out[i] = YF32 ? ((const float*)Yv)[yi] : bf2f(((const u16*)Yv)[yi]);
    }
}

extern "C" void kernel_launch(void* const* d_in, const int* in_sizes, int n_in,
                              void* d_out, int out_size, void* d_ws, size_t ws_size,
                              hipStream_t stream)
{
    const float* hidden = (const float*)d_in[0];
    const float* obs    = (const float*)d_in[1];
    const int*   dones  = (const int*)d_in[2];
    const int*   avail  = (const int*)d_in[3];
    const float* Wm     = (const float*)d_in[4];
    const float* bm     = (const float*)d_in[5];
    const float* lns    = (const float*)d_in[6];
    const float* lnb    = (const float*)d_in[7];
    const float* Wi     = (const float*)d_in[8];
    const float* bi     = (const float*)d_in[9];
    const float* Wh     = (const float*)d_in[10];
    const float* bhn    = (const float*)d_in[11];
    const float* Wo     = (const float*)d_in[12];
    const float* bo     = (const float*)d_in[13];
    const float* ln2s   = (const float*)d_in[14];
    const float* ln2b   = (const float*)d_in[15];
    const float* Wa     = (const float*)d_in[16];
    const float* ba     = (const float*)d_in[17];
    float* out = (float*)d_out;

    // workspace layout
    char* w = (char*)d_ws;
    u16* Wstk = (u16*)w;  w += (size_t)1536 * 1024 * 2;      // 3 MB: [gate*512+c][k], k<512=Wi, k>=512=Wh
    u16* WmT  = (u16*)w;  w += (size_t)3 * DDD * DDD * 2;
    u16* WoT  = (u16*)w;  w += (size_t)DDD * DDD * 2;
    int* meta = (int*)w;  w += 4096;                          // counts|offs|cursor|maxd
    int* counts = meta, *offs = meta + 256, *cursor = meta + 512, *maxd = meta + 768;
    int* depthA = (int*)w;  w += (size_t)MMM * 4;
    int* pidxA  = (int*)w;  w += (size_t)MMM * 4;
    int* list   = (int*)w;  w += (size_t)MMM * 4;
    u16* P = (u16*)w;       w += (size_t)MMM * DDD * 2;       // 64 MB
    void* Yv = (void*)w;
    const size_t base = (size_t)(w - (char*)d_ws);
    const bool yf32 = (ws_size >= base + (size_t)MMM * DDD * 4);

    // prep: weight transposes
    dim3 tgrid(16, 16);
    for (int l = 0; l < 3; l++)
        transpose_cvt_k<<<tgrid, 256, 0, stream>>>(Wm + (size_t)l * DDD * DDD, WmT + (size_t)l * DDD * DDD, DDD);
    transpose_cvt_k<<<tgrid, 256, 0, stream>>>(Wo, WoT, DDD);
    for (int g = 0; g < 3; g++) {
        transpose_cvt_k<<<tgrid, 256, 0, stream>>>(Wi + (size_t)g * DDD * DDD, Wstk + (size_t)g * 512 * 1024, 1024);
        transpose_cvt_k<<<tgrid, 256, 0, stream>>>(Wh + (size_t)g * DDD * DDD, Wstk + (size_t)g * 512 * 1024 + 512, 1024);
    }

    // depth lists
    init_meta_k<<<1, 256, 0, stream>>>(meta);
    depth_build_k<<<1, 256, 0, stream>>>(dones, depthA, pidxA, counts, maxd);
    scan_k<<<1, 256, 0, stream>>>(counts, offs);
    scatter_k<<<MMM / 256, 256, 0, stream>>>(depthA, offs, cursor, list);

    // encoder: obs -> P -> Y -> P
    u16* Yq = (u16*)Yv;
    gemm_bf16_k<true><<<dim3(MMM / 128, 4), 256, 0, stream>>>(obs, WmT, bm, P, DDD);
    ln_relu_k<<<dim3(MMM / 4), 256, 0, stream>>>(P, lns, lnb);
    gemm_bf16_k<false><<<dim3(MMM / 128, 4), 256, 0, stream>>>(P, WmT + (size_t)DDD * DDD, bm + DDD, Yq, DDD);
    ln_relu_k<<<dim3(MMM / 4), 256, 0, stream>>>(Yq, lns + DDD, lnb + DDD);
    gemm_bf16_k<false><<<dim3(MMM / 128, 4), 256, 0, stream>>>(Yq, WmT + (size_t)2 * DDD * DDD, bm + 2 * DDD, P, DDD);
    ln_relu_k<<<dim3(MMM / 4), 256, 0, stream>>>(P, lns + 2 * DDD, lnb + 2 * DDD);

    // cooperative depth-scheduled GRU
    {
        const u16* Earg = P;
        void* args[] = { (void*)&Earg, (void*)&hidden, (void*)&Wstk, (void*)&bi, (void*)&bhn,
                         (void*)&list, (void*)&offs, (void*)&counts, (void*)&maxd,
                         (void*)&pidxA, (void*)&Yv, (void*)&out };
        hipLaunchCooperativeKernel(yf32 ? (const void*)&gru_depth_k<true>
                                        : (const void*)&gru_depth_k<false>,
                                   dim3(512), dim3(192), args, 0, stream);
    }

    // head: Y -> P, LN, logits
    if (yf32)
        gemm_bf16_k<true><<<dim3(MMM / 128, 4), 256, 0, stream>>>(Yv, WoT, bo, P, DDD);
    else
        gemm_bf16_k<false><<<dim3(MMM / 128, 4), 256, 0, stream>>>(Yv, WoT, bo, P, DDD);
    ln_relu_k<<<dim3(MMM / 4), 256, 0, stream>>>(P, ln2s, ln2b);
    logits_k<<<dim3(MMM / 8), 256, 0, stream>>>(P, Wa, ba, avail, out + BBB * DDD);
}

// Round 4
// 3604.588 us; speedup vs baseline: 3.1431x; 1.2054x over previous
//
#include <hip/hip_runtime.h>
#include <hip/hip_bf16.h>
#include <math.h>

// PPOActorRNN on MI355X — round 4: restructured depth-parallel GRU.
// Coop GRU v2: job = 32-row tile x 128-gate-col panel (4 panels); each wave owns
// 32 gate-cols x {r,z,n} -> wave-local gate combine (no cross-wave traffic).
// Fused K=1024 over [E|h]; gate2 keeps separate x/h accumulators (kc split).
// Depth-0 tiles whose rows all have h_prev==0 skip the K>=512 half.
// Custom grid barrier (generation counter, device-scope atomics), persistent blocks.

#define TTT 256
#define BBB 256
#define DDD 512
#define ACT 32
#define MMM (TTT*BBB)

typedef short bf16x8 __attribute__((ext_vector_type(8)));
typedef float f32x4 __attribute__((ext_vector_type(4)));
typedef unsigned short u16;

__device__ inline u16 f2bf(float f) {
    unsigned int u = __float_as_uint(f);
    u += 0x7fffu + ((u >> 16) & 1u);
    return (u16)(u >> 16);
}
__device__ inline float bf2f(u16 h) { return __uint_as_float(((unsigned int)h) << 16); }

// ---------------- transpose + cvt: out[n*ostride + k] = bf16(in[k*512 + n]) ----
__global__ __launch_bounds__(256) void transpose_cvt_k(
    const float* __restrict__ in, u16* __restrict__ out, int ostride)
{
    __shared__ float tile[32][33];
    const int c = threadIdx.x & 31;
    const int r0 = threadIdx.x >> 5;
    const int bx = blockIdx.x, by = blockIdx.y;
#pragma unroll
    for (int p = 0; p < 4; p++) {
        int r = r0 + p * 8;
        tile[r][c] = in[(size_t)(by * 32 + r) * DDD + bx * 32 + c];
    }
    __syncthreads();
#pragma unroll
    for (int p = 0; p < 4; p++) {
        int r = r0 + p * 8;
        out[(size_t)(bx * 32 + r) * ostride + by * 32 + c] = f2bf(tile[c][r]);
    }
}

// ---------------- MFMA GEMM (parallel phases), unchanged from R3 ----------------
template<bool AF32>
__global__ __launch_bounds__(256) void gemm_bf16_k(
    const void* __restrict__ Aptr, const u16* __restrict__ Bt,
    const float* __restrict__ bias, u16* __restrict__ C, int N)
{
    __shared__ u16 As[128 * 64];
    __shared__ u16 Bs[128 * 64];
    const int tid = threadIdx.x;
    const int row0 = blockIdx.x * 128;
    const int col0 = blockIdx.y * 128;
    const int lane = tid & 63, wid = tid >> 6;
    const int wr = wid >> 1, wc = wid & 1;
    const int lm = lane & 15, lq = lane >> 4;

    f32x4 acc[4][4];
#pragma unroll
    for (int i = 0; i < 4; i++)
#pragma unroll
        for (int j = 0; j < 4; j++) acc[i][j] = (f32x4){0.f, 0.f, 0.f, 0.f};

    for (int kc = 0; kc < 8; kc++) {
        const int k0 = kc * 64;
#pragma unroll
        for (int p = 0; p < 4; p++) {
            int g = p * 256 + tid;
            int row = g >> 3, j = g & 7;
            bf16x8 v;
            if (AF32) {
                const float* s = (const float*)Aptr + (size_t)(row0 + row) * DDD + k0 + j * 8;
                float4 a0 = *(const float4*)s;
                float4 a1 = *(const float4*)(s + 4);
                v[0] = (short)f2bf(a0.x); v[1] = (short)f2bf(a0.y);
                v[2] = (short)f2bf(a0.z); v[3] = (short)f2bf(a0.w);
                v[4] = (short)f2bf(a1.x); v[5] = (short)f2bf(a1.y);
                v[6] = (short)f2bf(a1.z); v[7] = (short)f2bf(a1.w);
            } else {
                v = *(const bf16x8*)((const u16*)Aptr + (size_t)(row0 + row) * DDD + k0 + j * 8);
            }
            *(bf16x8*)(As + row * 64 + ((j ^ (row & 7)) << 3)) = v;
        }
#pragma unroll
        for (int p = 0; p < 4; p++) {
            int g = p * 256 + tid;
            int n = g >> 3, j = g & 7;
            bf16x8 v = *(const bf16x8*)(Bt + (size_t)(col0 + n) * DDD + k0 + j * 8);
            *(bf16x8*)(Bs + n * 64 + ((j ^ (n & 7)) << 3)) = v;
        }
        __syncthreads();
#pragma unroll
        for (int ks = 0; ks < 2; ks++) {
            bf16x8 af[4], bfr[4];
#pragma unroll
            for (int i = 0; i < 4; i++) {
                int row = wr * 64 + i * 16 + lm;
                af[i] = *(const bf16x8*)(As + row * 64 + (((ks * 4 + lq) ^ (row & 7)) << 3));
            }
#pragma unroll
            for (int j = 0; j < 4; j++) {
                int n = wc * 64 + j * 16 + lm;
                bfr[j] = *(const bf16x8*)(Bs + n * 64 + (((ks * 4 + lq) ^ (n & 7)) << 3));
            }
#pragma unroll
            for (int i = 0; i < 4; i++)
#pragma unroll
                for (int j = 0; j < 4; j++)
                    acc[i][j] = __builtin_amdgcn_mfma_f32_16x16x32_bf16(af[i], bfr[j], acc[i][j], 0, 0, 0);
        }
        __syncthreads();
    }
#pragma unroll
    for (int j = 0; j < 4; j++) {
        int col = col0 + wc * 64 + j * 16 + lm;
        float bj = bias[col];
#pragma unroll
        for (int i = 0; i < 4; i++) {
            int rb = row0 + wr * 64 + i * 16 + lq * 4;
#pragma unroll
            for (int r = 0; r < 4; r++)
                C[(size_t)(rb + r) * N + col] = f2bf(acc[i][j][r] + bj);
        }
    }
}

// ---------------- LayerNorm + ReLU in-place on bf16 [M x 512] ----------------
__global__ __launch_bounds__(256) void ln_relu_k(
    u16* __restrict__ X, const float* __restrict__ gamma, const float* __restrict__ beta)
{
    const int tid = threadIdx.x;
    const int lane = tid & 63;
    const size_t row = (size_t)blockIdx.x * 4 + (tid >> 6);
    const int c0 = lane * 8;
    u16* px = X + row * DDD + c0;
    bf16x8 v = *(const bf16x8*)px;
    float f[8]; float s = 0.f, s2 = 0.f;
#pragma unroll
    for (int i = 0; i < 8; i++) { f[i] = bf2f((u16)v[i]); s += f[i]; s2 += f[i] * f[i]; }
#pragma unroll
    for (int off = 32; off; off >>= 1) { s += __shfl_xor(s, off); s2 += __shfl_xor(s2, off); }
    float mu = s * (1.f / (float)DDD);
    float rs = rsqrtf(s2 * (1.f / (float)DDD) - mu * mu + 1e-6f);
    float4 g0 = *(const float4*)(gamma + c0), g1 = *(const float4*)(gamma + c0 + 4);
    float4 b0 = *(const float4*)(beta + c0),  b1 = *(const float4*)(beta + c0 + 4);
    float gg[8] = {g0.x, g0.y, g0.z, g0.w, g1.x, g1.y, g1.z, g1.w};
    float bb[8] = {b0.x, b0.y, b0.z, b0.w, b1.x, b1.y, b1.z, b1.w};
    bf16x8 o;
#pragma unroll
    for (int i = 0; i < 8; i++) {
        float yv = (f[i] - mu) * rs * gg[i] + bb[i];
        o[i] = (short)f2bf(fmaxf(yv, 0.f));
    }
    *(bf16x8*)px = o;
}

// ---------------- logits ----------------
__global__ __launch_bounds__(256) void logits_k(
    const u16* __restrict__ AM, const float* __restrict__ Wa,
    const float* __restrict__ ba, const int* __restrict__ avail,
    float* __restrict__ out)
{
    __shared__ float xs[8][DDD];
    const int tid = threadIdx.x;
    const size_t row0 = (size_t)blockIdx.x * 8;
    for (int g = tid; g < 8 * 64; g += 256) {
        int r = g >> 6, c8 = (g & 63) * 8;
        bf16x8 v = *(const bf16x8*)(AM + (row0 + r) * DDD + c8);
#pragma unroll
        for (int i = 0; i < 8; i++) xs[r][c8 + i] = bf2f((u16)v[i]);
    }
    __syncthreads();
    const int r = tid >> 5, a = tid & 31;
    float acc = 0.f;
    for (int k = 0; k < DDD; k += 4) {
        float4 xv = *(const float4*)&xs[r][k];
        acc = fmaf(xv.x, Wa[(k + 0) * ACT + a], acc);
        acc = fmaf(xv.y, Wa[(k + 1) * ACT + a], acc);
        acc = fmaf(xv.z, Wa[(k + 2) * ACT + a], acc);
        acc = fmaf(xv.w, Wa[(k + 3) * ACT + a], acc);
    }
    size_t o = (row0 + r) * ACT + a;
    float v = acc + ba[a];
    if (avail[o] == 0) v -= 1e10f;
    out[o] = v;
}

// ---------------- list building ----------------
// depth histogram via LDS (single block, 256 threads = batch columns)
__global__ __launch_bounds__(256) void depth_build_k(
    const int* __restrict__ dones,
    int* __restrict__ depthA, int* __restrict__ pidxA,
    int* __restrict__ counts, int* __restrict__ maxd)
{
    __shared__ int lc[256];
    __shared__ int lmax;
    const int b = threadIdx.x;
    lc[b] = 0;
    if (b == 0) lmax = 0;
    __syncthreads();
    int dprev = 0, mx = 0;
    for (int t = 0; t < TTT; t++) {
        int pos = t * BBB + b;
        int d, pi;
        if (dones[pos] != 0)       { d = 0; pi = -1; }
        else if (t == 0)           { d = 0; pi = -2 - b; }
        else                       { d = dprev + 1; pi = pos - BBB; }
        depthA[pos] = d; pidxA[pos] = pi;
        atomicAdd(&lc[d], 1);
        mx = max(mx, d);
        dprev = d;
    }
    atomicMax(&lmax, mx);
    __syncthreads();
    counts[b] = lc[b];
    if (b == 0) *maxd = lmax;
}

__global__ void scan_k(const int* __restrict__ counts, int* __restrict__ offs)
{
    if (threadIdx.x == 0) {
        int s = 0;
        for (int i = 0; i < 256; i++) { offs[i] = s; s += counts[i]; }
    }
}

// LDS-aggregated scatter: block-local ranks, one global atomic per (block,depth)
__global__ __launch_bounds__(256) void scatter_k(
    const int* __restrict__ depthA, const int* __restrict__ offs,
    int* __restrict__ cursor, int* __restrict__ list)
{
    __shared__ int lcnt[256];
    __shared__ int lbase[256];
    const int tid = threadIdx.x;
    lcnt[tid] = 0;
    __syncthreads();
    int pos = blockIdx.x * 256 + tid;
    int d = depthA[pos];
    int rank = atomicAdd(&lcnt[d], 1);
    __syncthreads();
    int c = lcnt[tid];
    lbase[tid] = c ? atomicAdd(&cursor[tid], c) : 0;
    __syncthreads();
    list[offs[d] + lbase[d] + rank] = pos;
}

// ---------------- lightweight grid barrier ----------------
__device__ inline void grid_barrier(int* cnt, int* gen, int nblk)
{
    __syncthreads();
    if (threadIdx.x == 0) {
        __threadfence();   // publish this block's Y writes device-wide
        int g = __hip_atomic_load(gen, __ATOMIC_ACQUIRE, __HIP_MEMORY_SCOPE_AGENT);
        int a = __hip_atomic_fetch_add(cnt, 1, __ATOMIC_ACQ_REL, __HIP_MEMORY_SCOPE_AGENT);
        if (a == nblk - 1) {
            __hip_atomic_store(cnt, 0, __ATOMIC_RELAXED, __HIP_MEMORY_SCOPE_AGENT);
            __hip_atomic_store(gen, g + 1, __ATOMIC_RELEASE, __HIP_MEMORY_SCOPE_AGENT);
        } else {
            while (__hip_atomic_load(gen, __ATOMIC_ACQUIRE, __HIP_MEMORY_SCOPE_AGENT) == g)
                __builtin_amdgcn_s_sleep(1);
        }
        __threadfence();
    }
    __syncthreads();
}

// ---------------- coop depth-scheduled GRU v2 ----------------
// block = 256 thr (4 waves). job = 32-row tile x 128-gate-col panel.
// wave w owns gate-cols [panel*128 + w*32, +32) for ALL 3 gates.
// acc: a01[mt][4] = gates r,z (full K); aX/aH[mt][2] = gate n x-part / h-part.
template<bool YF32>
__global__ __launch_bounds__(256, 2) void gru_depth_k(
    const u16* __restrict__ E, const float* __restrict__ hidden,
    const u16* __restrict__ Wstk, const float* __restrict__ bi,
    const float* __restrict__ bhn,
    const int* __restrict__ list, const int* __restrict__ offs,
    const int* __restrict__ counts, const int* __restrict__ maxd,
    const int* __restrict__ pidxA,
    void* __restrict__ Yv, float* __restrict__ hid_out,
    int* __restrict__ barCnt, int* __restrict__ barGen)
{
    __shared__ u16 As[32 * 256];         // 16 KB, one 256-K chunk of 32 rows
    __shared__ int posL[32], pidxL[32];
    __shared__ int sAnyH;
    const int tid = threadIdx.x;
    const int w = tid >> 6, lane = tid & 63;
    const int lm = lane & 15, lq = lane >> 4;
    const int nblk = gridDim.x;

    const int MD = *maxd;
    for (int d = 0; d <= MD; d++) {
        const int nd = counts[d];
        const int off = offs[d];
        const int njobs = ((nd + 31) >> 5) << 2;   // tiles * 4 panels
        for (int j = blockIdx.x; j < njobs; j += nblk) {
            const int rt = j >> 2, panel = j & 3;
            // load position list slice; wave0 ballots "any row has nonzero h_prev"
            bool hasH = false;
            if (tid < 32) {
                int idx = rt * 32 + tid;
                int p = (idx < nd) ? list[off + idx] : -1;
                int pi = (p >= 0) ? pidxA[p] : -1;
                posL[tid] = p;
                pidxL[tid] = pi;
                hasH = (p >= 0) && (pi != -1);
            }
            if (tid < 64) {
                unsigned long long m = __ballot(hasH);
                if (tid == 0) sAnyH = (m != 0ULL);
            }
            __syncthreads();
            const bool skipH = !sAnyH;

            f32x4 a01[2][4], aX[2][2], aH[2][2];
#pragma unroll
            for (int mt = 0; mt < 2; mt++) {
#pragma unroll
                for (int q = 0; q < 4; q++) a01[mt][q] = (f32x4){0.f, 0.f, 0.f, 0.f};
#pragma unroll
                for (int q = 0; q < 2; q++) {
                    aX[mt][q] = (f32x4){0.f, 0.f, 0.f, 0.f};
                    aH[mt][q] = (f32x4){0.f, 0.f, 0.f, 0.f};
                }
            }

            const int cb = panel * 128 + w * 32;
            const int nkc = skipH ? 2 : 4;
            for (int kc = 0; kc < nkc; kc++) {
                // stage A chunk: 32 rows x 256 K (gathered rows)
#pragma unroll
                for (int it = 0; it < 4; it++) {
                    int g = it * 256 + tid;
                    int row = g >> 5, jg = g & 31;
                    int kglob = kc * 256 + jg * 8;
                    bf16x8 v = (bf16x8){0, 0, 0, 0, 0, 0, 0, 0};
                    int p = posL[row];
                    if (p >= 0) {
                        if (kglob < 512) {
                            v = *(const bf16x8*)(E + (size_t)p * DDD + kglob);
                        } else {
                            int k2 = kglob - 512;
                            int pi = pidxL[row];
                            if (pi >= 0) {
                                if (YF32) {
                                    const float* s = (const float*)Yv + (size_t)pi * DDD + k2;
                                    float4 a0 = *(const float4*)s;
                                    float4 a1 = *(const float4*)(s + 4);
                                    v[0] = (short)f2bf(a0.x); v[1] = (short)f2bf(a0.y);
                                    v[2] = (short)f2bf(a0.z); v[3] = (short)f2bf(a0.w);
                                    v[4] = (short)f2bf(a1.x); v[5] = (short)f2bf(a1.y);
                                    v[6] = (short)f2bf(a1.z); v[7] = (short)f2bf(a1.w);
                                } else {
                                    v = *(const bf16x8*)((const u16*)Yv + (size_t)pi * DDD + k2);
                                }
                            } else if (pi <= -2) {
                                const float* s = hidden + (size_t)(-pi - 2) * DDD + k2;
                                float4 a0 = *(const float4*)s;
                                float4 a1 = *(const float4*)(s + 4);
                                v[0] = (short)f2bf(a0.x); v[1] = (short)f2bf(a0.y);
                                v[2] = (short)f2bf(a0.z); v[3] = (short)f2bf(a0.w);
                                v[4] = (short)f2bf(a1.x); v[5] = (short)f2bf(a1.y);
                                v[6] = (short)f2bf(a1.z); v[7] = (short)f2bf(a1.w);
                            }
                        }
                    }
                    *(bf16x8*)(As + row * 256 + ((jg ^ (row & 31)) << 3)) = v;
                }
                __syncthreads();

                const bool xpart = (kc < 2);
#pragma unroll
                for (int s = 0; s < 8; s++) {
                    const int kg = kc * 256 + s * 32;
                    bf16x8 bf[6];
#pragma unroll
                    for (int ct = 0; ct < 6; ct++) {
                        int gate = ct >> 1;
                        int nglob = gate * 512 + cb + ((ct & 1) << 4) + lm;
                        bf[ct] = *(const bf16x8*)(Wstk + (size_t)nglob * 1024 + kg + lq * 8);
                    }
#pragma unroll
                    for (int mt = 0; mt < 2; mt++) {
                        int row = mt * 16 + lm;
                        int jgr = s * 4 + lq;
                        bf16x8 af = *(const bf16x8*)(As + row * 256 + ((jgr ^ (row & 31)) << 3));
                        a01[mt][0] = __builtin_amdgcn_mfma_f32_16x16x32_bf16(af, bf[0], a01[mt][0], 0, 0, 0);
                        a01[mt][1] = __builtin_amdgcn_mfma_f32_16x16x32_bf16(af, bf[1], a01[mt][1], 0, 0, 0);
                        a01[mt][2] = __builtin_amdgcn_mfma_f32_16x16x32_bf16(af, bf[2], a01[mt][2], 0, 0, 0);
                        a01[mt][3] = __builtin_amdgcn_mfma_f32_16x16x32_bf16(af, bf[3], a01[mt][3], 0, 0, 0);
                        if (xpart) {
                            aX[mt][0] = __builtin_amdgcn_mfma_f32_16x16x32_bf16(af, bf[4], aX[mt][0], 0, 0, 0);
                            aX[mt][1] = __builtin_amdgcn_mfma_f32_16x16x32_bf16(af, bf[5], aX[mt][1], 0, 0, 0);
                        } else {
                            aH[mt][0] = __builtin_amdgcn_mfma_f32_16x16x32_bf16(af, bf[4], aH[mt][0], 0, 0, 0);
                            aH[mt][1] = __builtin_amdgcn_mfma_f32_16x16x32_bf16(af, bf[5], aH[mt][1], 0, 0, 0);
                        }
                    }
                }
                __syncthreads();
            }

            // wave-local gate combine + Y write
#pragma unroll
            for (int mt = 0; mt < 2; mt++) {
#pragma unroll
                for (int r = 0; r < 4; r++) {
                    int row = mt * 16 + lq * 4 + r;
                    int p = posL[row];
                    if (p < 0) continue;
                    int pi = pidxL[row];
#pragma unroll
                    for (int ct = 0; ct < 2; ct++) {
                        int cglob = cb + ct * 16 + lm;
                        float rpre = a01[mt][ct][r]     + bi[cglob];
                        float zpre = a01[mt][2 + ct][r] + bi[512 + cglob];
                        float xn   = aX[mt][ct][r]      + bi[1024 + cglob];
                        float hn   = aH[mt][ct][r]      + bhn[cglob];
                        float rg = 1.f / (1.f + __expf(-rpre));
                        float zg = 1.f / (1.f + __expf(-zpre));
                        float targ = xn + rg * hn;
                        float t2 = __expf(-2.f * fabsf(targ));
                        float ng = copysignf((1.f - t2) / (1.f + t2), targ);
                        float hp = 0.f;
                        if (pi >= 0)
                            hp = YF32 ? ((const float*)Yv)[(size_t)pi * DDD + cglob]
                                      : bf2f(((const u16*)Yv)[(size_t)pi * DDD + cglob]);
                        else if (pi <= -2)
                            hp = hidden[(size_t)(-pi - 2) * DDD + cglob];
                        float hnew = (1.f - zg) * ng + zg * hp;
                        if (YF32) ((float*)Yv)[(size_t)p * DDD + cglob] = hnew;
                        else      ((u16*)Yv)[(size_t)p * DDD + cglob] = f2bf(hnew);
                    }
                }
            }
            __syncthreads();   // protect posL/As for next job
        }
        grid_barrier(barCnt, barGen, nblk);
    }

    // final hidden: out[b*512+c] = Y[(255*256+b)*512+c]
    for (int i = blockIdx.x * 256 + tid; i < BBB * DDD; i += nblk * 256) {
        int b = i >> 9, c = i & 511;
        size_t yi = (size_t)(65280 + b) * DDD + c;
        hid_out[i] = YF32 ? ((const float*)Yv)[yi] : bf2f(((const u16*)Yv)[yi]);
    }
}

extern "C" void kernel_launch(void* const* d_in, const int* in_sizes, int n_in,
                              void* d_out, int out_size, void* d_ws, size_t ws_size,
                              hipStream_t stream)
{
    const float* hidden = (const float*)d_in[0];
    const float* obs    = (const float*)d_in[1];
    const int*   dones  = (const int*)d_in[2];
    const int*   avail  = (const int*)d_in[3];
    const float* Wm     = (const float*)d_in[4];
    const float* bm     = (const float*)d_in[5];
    const float* lns    = (const float*)d_in[6];
    const float* lnb    = (const float*)d_in[7];
    const float* Wi     = (const float*)d_in[8];
    const float* bi     = (const float*)d_in[9];
    const float* Wh     = (const float*)d_in[10];
    const float* bhn    = (const float*)d_in[11];
    const float* Wo     = (const float*)d_in[12];
    const float* bo     = (const float*)d_in[13];
    const float* ln2s   = (const float*)d_in[14];
    const float* ln2b   = (const float*)d_in[15];
    const float* Wa     = (const float*)d_in[16];
    const float* ba     = (const float*)d_in[17];
    float* out = (float*)d_out;

    // workspace layout
    char* w = (char*)d_ws;
    u16* Wstk = (u16*)w;  w += (size_t)1536 * 1024 * 2;      // 3 MB
    u16* WmT  = (u16*)w;  w += (size_t)3 * DDD * DDD * 2;
    u16* WoT  = (u16*)w;  w += (size_t)DDD * DDD * 2;
    int* meta = (int*)w;  w += 4096;
    int* counts = meta, *offs = meta + 256, *cursor = meta + 512, *maxd = meta + 768;
    int* barCnt = meta + 800, *barGen = meta + 832;          // separate cachelines
    int* depthA = (int*)w;  w += (size_t)MMM * 4;
    int* pidxA  = (int*)w;  w += (size_t)MMM * 4;
    int* list   = (int*)w;  w += (size_t)MMM * 4;
    u16* P = (u16*)w;       w += (size_t)MMM * DDD * 2;      // 64 MB
    void* Yv = (void*)w;
    const size_t base = (size_t)(w - (char*)d_ws);
    const bool yf32 = (ws_size >= base + (size_t)MMM * DDD * 4);

    // prep: weight transposes + meta zero
    dim3 tgrid(16, 16);
    for (int l = 0; l < 3; l++)
        transpose_cvt_k<<<tgrid, 256, 0, stream>>>(Wm + (size_t)l * DDD * DDD, WmT + (size_t)l * DDD * DDD, DDD);
    transpose_cvt_k<<<tgrid, 256, 0, stream>>>(Wo, WoT, DDD);
    for (int g = 0; g < 3; g++) {
        transpose_cvt_k<<<tgrid, 256, 0, stream>>>(Wi + (size_t)g * DDD * DDD, Wstk + (size_t)g * 512 * 1024, 1024);
        transpose_cvt_k<<<tgrid, 256, 0, stream>>>(Wh + (size_t)g * DDD * DDD, Wstk + (size_t)g * 512 * 1024 + 512, 1024);
    }
    hipMemsetAsync(meta, 0, 4096, stream);

    // depth lists
    depth_build_k<<<1, 256, 0, stream>>>(dones, depthA, pidxA, counts, maxd);
    scan_k<<<1, 64, 0, stream>>>(counts, offs);
    scatter_k<<<MMM / 256, 256, 0, stream>>>(depthA, offs, cursor, list);

    // encoder: obs -> P -> Y -> P
    u16* Yq = (u16*)Yv;
    gemm_bf16_k<true><<<dim3(MMM / 128, 4), 256, 0, stream>>>(obs, WmT, bm, P, DDD);
    ln_relu_k<<<dim3(MMM / 4), 256, 0, stream>>>(P, lns, lnb);
    gemm_bf16_k<false><<<dim3(MMM / 128, 4), 256, 0, stream>>>(P, WmT + (size_t)DDD * DDD, bm + DDD, Yq, DDD);
    ln_relu_k<<<dim3(MMM / 4), 256, 0, stream>>>(Yq, lns + DDD, lnb + DDD);
    gemm_bf16_k<false><<<dim3(MMM / 128, 4), 256, 0, stream>>>(Yq, WmT + (size_t)2 * DDD * DDD, bm + 2 * DDD, P, DDD);
    ln_relu_k<<<dim3(MMM / 4), 256, 0, stream>>>(P, lns + 2 * DDD, lnb + 2 * DDD);

    // persistent-block GRU; grid sized to guaranteed co-residency
    {
        const void* fptr = yf32 ? (const void*)gru_depth_k<true>
                                : (const void*)gru_depth_k<false>;
        int occ = 0;
        hipError_t e = hipOccupancyMaxActiveBlocksPerMultiprocessor(&occ, fptr, 256, 0);
        if (e != hipSuccess || occ < 1) occ = 2;
        if (occ > 4) occ = 4;
        dim3 grid(occ * 256);
        if (yf32)
            gru_depth_k<true><<<grid, 256, 0, stream>>>(
                P, hidden, Wstk, bi, bhn, list, offs, counts, maxd, pidxA,
                Yv, out, barCnt, barGen);
        else
            gru_depth_k<false><<<grid, 256, 0, stream>>>(
                P, hidden, Wstk, bi, bhn, list, offs, counts, maxd, pidxA,
                Yv, out, barCnt, barGen);
    }

    // head: Y -> P, LN, logits
    if (yf32)
        gemm_bf16_k<true><<<dim3(MMM / 128, 4), 256, 0, stream>>>(Yv, WoT, bo, P, DDD);
    else
        gemm_bf16_k<false><<<dim3(MMM / 128, 4), 256, 0, stream>>>(Yv, WoT, bo, P, DDD);
    ln_relu_k<<<dim3(MMM / 4), 256, 0, stream>>>(P, ln2s, ln2b);
    logits_k<<<dim3(MMM / 8), 256, 0, stream>>>(P, Wa, ba, avail, out + BBB * DDD);
}